// Round 11
// baseline (24.208 us; speedup 1.0000x reference)
//
#include <hip/hip_runtime.h>
#include <math.h>

#define Bc 4
#define Cc 128
#define Pc 64
#define PLANE 576      // 24*24
#define VOL   13824    // 24^3
#define NI    (-INFINITY)

// One wave per (proposal, 4 channels {s, s+32, s+64, s+96}), processed as
// TWO SEQUENTIAL channel-pairs ({s,s+64} then {s+32,s+96}) that REUSE the
// same accumulator registers -> R10's register footprint (+8 for pass-0's
// folded octants), half R10's wave count, prologue shared by 4 channels.
// Loop = R7's 3 uniform scalar d-segments (no unroll pragma). Shared
// w-biases; row validity folded in h-masks. Epilogue: per-pass xor-32 fold
// (merges channel pair), then two independent select-exchange trees (ILP).

struct Acc { float v00, v01, v10, v11; };   // [d-region][w-region]

template<int RMODE>   // 0: d-region0, 1: d-region1, 2: both (overlap plane)
__device__ __forceinline__ void upd(Acc& a, float t0, float t1) {
    if (RMODE != 1) { a.v00 = fmaxf(a.v00, t0); a.v01 = fmaxf(a.v01, t1); }
    if (RMODE != 0) { a.v10 = fmaxf(a.v10, t0); a.v11 = fmaxf(a.v11, t1); }
}

#define TREE(v, B) fmaxf(fmaxf((v).x + (B).x, (v).y + (B).y),               \
                         fmaxf((v).z + (B).z, (v).w + (B).w))

template<int RMODE>
__device__ __forceinline__ void run_seg(
    const float* __restrict__& pA, const float* __restrict__& pB, int n,
    bool c1p, bool c2p, const int fcl[3],
    const float4 B0, const float4 B1, Acc* aA, Acc* aB)
{
    for (int i = 0; i < n; ++i) {
        {
            float4 vA = *(const float4*)(pA + fcl[0]);
            float4 vB = *(const float4*)(pB + fcl[0]);
            upd<RMODE>(aA[0], TREE(vA, B0), TREE(vA, B1));
            upd<RMODE>(aB[0], TREE(vB, B0), TREE(vB, B1));
        }
        if (c1p) {
            float4 vA = *(const float4*)(pA + fcl[1]);
            float4 vB = *(const float4*)(pB + fcl[1]);
            upd<RMODE>(aA[1], TREE(vA, B0), TREE(vA, B1));
            upd<RMODE>(aB[1], TREE(vB, B0), TREE(vB, B1));
        }
        if (c2p) {
            float4 vA = *(const float4*)(pA + fcl[2]);
            float4 vB = *(const float4*)(pB + fcl[2]);
            upd<RMODE>(aA[2], TREE(vA, B0), TREE(vA, B1));
            upd<RMODE>(aB[2], TREE(vB, B0), TREE(vB, B1));
        }
        pA += PLANE; pB += PLANE;
    }
}

// One channel pair over the whole crop; returns folded octants x[8]
// (lanes<32 hold channel A's octants, lanes>=32 channel B's).
__device__ __forceinline__ void run_pass(
    const float* __restrict__ pA, const float* __restrict__ pB,
    int n0, int n1, int n2, bool c1p, bool c2p, const int fcl[3],
    const float4 B0, const float4 B1,
    const bool h0m[3], const bool h1m[3], bool lo, float x[8])
{
    Acc aA[3], aB[3];
#pragma unroll
    for (int K = 0; K < 3; ++K) {
        aA[K].v00=NI; aA[K].v01=NI; aA[K].v10=NI; aA[K].v11=NI;
        aB[K].v00=NI; aB[K].v01=NI; aB[K].v10=NI; aB[K].v11=NI;
    }

    run_seg<0>(pA, pB, n0, c1p, c2p, fcl, B0, B1, aA, aB);
    run_seg<2>(pA, pB, n1, c1p, c2p, fcl, B0, B1, aA, aB);
    run_seg<1>(pA, pB, n2, c1p, c2p, fcl, B0, B1, aA, aB);

    float oA[8], oB[8];
#pragma unroll
    for (int j = 0; j < 8; ++j) { oA[j] = NI; oB[j] = NI; }
#pragma unroll
    for (int K = 0; K < 3; ++K) {
        if (K == 1 && !c1p) continue;
        if (K == 2 && !c2p) continue;
        oA[0] = fmaxf(oA[0], h0m[K] ? aA[K].v00 : NI);
        oA[1] = fmaxf(oA[1], h0m[K] ? aA[K].v01 : NI);
        oA[2] = fmaxf(oA[2], h1m[K] ? aA[K].v00 : NI);
        oA[3] = fmaxf(oA[3], h1m[K] ? aA[K].v01 : NI);
        oA[4] = fmaxf(oA[4], h0m[K] ? aA[K].v10 : NI);
        oA[5] = fmaxf(oA[5], h0m[K] ? aA[K].v11 : NI);
        oA[6] = fmaxf(oA[6], h1m[K] ? aA[K].v10 : NI);
        oA[7] = fmaxf(oA[7], h1m[K] ? aA[K].v11 : NI);
        oB[0] = fmaxf(oB[0], h0m[K] ? aB[K].v00 : NI);
        oB[1] = fmaxf(oB[1], h0m[K] ? aB[K].v01 : NI);
        oB[2] = fmaxf(oB[2], h1m[K] ? aB[K].v00 : NI);
        oB[3] = fmaxf(oB[3], h1m[K] ? aB[K].v01 : NI);
        oB[4] = fmaxf(oB[4], h0m[K] ? aB[K].v10 : NI);
        oB[5] = fmaxf(oB[5], h0m[K] ? aB[K].v11 : NI);
        oB[6] = fmaxf(oB[6], h1m[K] ? aB[K].v10 : NI);
        oB[7] = fmaxf(oB[7], h1m[K] ? aB[K].v11 : NI);
    }
#pragma unroll
    for (int j = 0; j < 8; ++j) {
        float keep = lo ? oA[j] : oB[j];
        float send = lo ? oB[j] : oA[j];
        x[j] = fmaxf(keep, __shfl_xor(send, 32));
    }
}

// Select-exchange reduce over 32-lane halves (octant bit -> lane bit).
__device__ __forceinline__ float oct_reduce32(const float x[8], int lane) {
    const bool b0 = lane & 1, b1 = lane & 2, b2 = lane & 4;
    float m0 = fmaxf(b0 ? x[1] : x[0], __shfl_xor(b0 ? x[0] : x[1], 1));
    float m1 = fmaxf(b0 ? x[3] : x[2], __shfl_xor(b0 ? x[2] : x[3], 1));
    float m2 = fmaxf(b0 ? x[5] : x[4], __shfl_xor(b0 ? x[4] : x[5], 1));
    float m3 = fmaxf(b0 ? x[7] : x[6], __shfl_xor(b0 ? x[6] : x[7], 1));
    float n0 = fmaxf(b1 ? m1 : m0, __shfl_xor(b1 ? m0 : m1, 2));
    float n1 = fmaxf(b1 ? m3 : m2, __shfl_xor(b1 ? m2 : m3, 2));
    float v  = fmaxf(b2 ? n1 : n0, __shfl_xor(b2 ? n0 : n1, 4));
    v = fmaxf(v, __shfl_xor(v, 8));
    v = fmaxf(v, __shfl_xor(v, 16));
    return v;
}

__global__ __launch_bounds__(256) void crop_pool_kernel(
    const float* __restrict__ fm, const int* __restrict__ corners,
    const int* __restrict__ scale_p, float* __restrict__ out)
{
    const int lane = threadIdx.x & 63;
    const int wid  = threadIdx.x >> 6;   // 0..3
    const int bp   = blockIdx.x >> 3;    // 8 consecutive blocks per proposal
    const int slot = (blockIdx.x & 7) * 4 + wid;   // 0..31
    const int b    = bp >> 6;            // P = 64

    const float inv = 1.0f / (float)scale_p[0];   // uniform; exact-floor mul

    // Per-axis bounds (k: 0->D, 1->H, 2->W), uniform -> SGPR.
    int s[3], e[3], m0a[3], m1a[3];
#pragma unroll
    for (int k = 0; k < 3; ++k) {
        int c0 = corners[(bp * 2 + 0) * 3 + k];
        int c1 = corners[(bp * 2 + 1) * 3 + k];
        int p1v = (int)((float)c0 * inv);     // == c0/scale (c0 in [0,95])
        p1v = p1v > 21 ? 21 : p1v;
        int p2v = (int)((float)c1 * inv);
        if (p2v - p1v < 2) p2v = p1v + 2;
        int ee = p2v < 24 ? p2v : 24;
        int n  = ee - p1v;                    // 2..23
        s[k]   = __builtin_amdgcn_readfirstlane(p1v);
        e[k]   = __builtin_amdgcn_readfirstlane(ee);
        m0a[k] = __builtin_amdgcn_readfirstlane(p1v + ((n + 1) >> 1)); // r0 end
        m1a[k] = __builtin_amdgcn_readfirstlane(p1v + (n >> 1));       // r1 start
    }

    const int n0 = m1a[0] - s[0];            // d-segment lengths
    const int n1 = m0a[0] - m1a[0];
    const int n2 = e[0] - m0a[0];
    const int sh = s[1], eh = e[1], nh = eh - sh;
    const int m0h = m0a[1], m1h = m1a[1];
    const int sw = s[2], ew = e[2], m0w = m0a[2], m1w = m1a[2];

    const int qb = sw & ~3;                            // aligned w base
    const int Q  = ((sw & 3) + (ew - sw) + 3) >> 2;    // quads per row, 1..7
    const unsigned M = (65536u + (unsigned)Q - 1) / (unsigned)Q;
    const int R = (int)((64u * M) >> 16);              // rows per sweep = 64/Q

    const int r = (int)(((unsigned)lane * M) >> 16);   // lane -> row in chunk
    const int q = lane - r * Q;
    const int wbase = qb + 4 * q;                      // 4-aligned, <= 20

    const bool c1p = nh > R;                 // wave-uniform chunk presence
    const bool c2p = nh > 2 * R;

    // Shared w-biases (row validity lives in the h-masks instead)
    float4 B0, B1;
    {
        int wt;
        wt = wbase + 0;
        B0.x = (wt >= sw  && wt < m0w) ? 0.0f : NI;
        B1.x = (wt >= m1w && wt < ew ) ? 0.0f : NI;
        wt = wbase + 1;
        B0.y = (wt >= sw  && wt < m0w) ? 0.0f : NI;
        B1.y = (wt >= m1w && wt < ew ) ? 0.0f : NI;
        wt = wbase + 2;
        B0.z = (wt >= sw  && wt < m0w) ? 0.0f : NI;
        B1.z = (wt >= m1w && wt < ew ) ? 0.0f : NI;
        wt = wbase + 3;
        B0.w = (wt >= sw  && wt < m0w) ? 0.0f : NI;
        B1.w = (wt >= m1w && wt < ew ) ? 0.0f : NI;
    }

    // Per-chunk row state: clamped in-plane offset + h-masks (validity folded)
    int  fcl[3];
    bool h0m[3], h1m[3];
#pragma unroll
    for (int K = 0; K < 3; ++K) {
        const int  hrow = K * R + r;
        const int  h    = sh + hrow;
        const bool va   = hrow < nh;
        const int  f    = h * 24 + wbase;
        fcl[K] = f < (PLANE - 4) ? f : (PLANE - 4);
        h0m[K] = va && (h <  m0h);
        h1m[K] = va && (h >= m1h);
    }

    const bool   lo   = lane < 32;
    const size_t doff = (size_t)s[0] * PLANE;
    const float* base = fm + (size_t)b * Cc * VOL + doff;

    // Pass 0: channels {slot, slot+64}
    float x0[8];
    run_pass(base + (size_t)(slot     ) * VOL, base + (size_t)(slot + 64) * VOL,
             n0, n1, n2, c1p, c2p, fcl, B0, B1, h0m, h1m, lo, x0);
    // Pass 1: channels {slot+32, slot+96}  (reuses the same acc registers)
    float x1[8];
    run_pass(base + (size_t)(slot + 32) * VOL, base + (size_t)(slot + 96) * VOL,
             n0, n1, n2, c1p, c2p, fcl, B0, B1, h0m, h1m, lo, x1);

    // Two independent select-exchange trees (ILP-overlapped), two stores.
    const float v0 = oct_reduce32(x0, lane);
    const float v1 = oct_reduce32(x1, lane);

    if ((lane & 31) < 8) {
        const int c0 = lo ? slot      : slot + 64;
        const int c1 = lo ? slot + 32 : slot + 96;
        out[((size_t)bp * Cc + c0) * 8 + (lane & 7)] = v0;
        out[((size_t)bp * Cc + c1) * 8 + (lane & 7)] = v1;
    }
}

extern "C" void kernel_launch(void* const* d_in, const int* in_sizes, int n_in,
                              void* d_out, int out_size, void* d_ws, size_t ws_size,
                              hipStream_t stream) {
    const float* fm      = (const float*)d_in[0];
    const int*   corners = (const int*)d_in[1];
    const int*   scale   = (const int*)d_in[2];
    float*       out     = (float*)d_out;

    dim3 grid(Bc * Pc * 8);    // 2048 blocks: one wave per (proposal, 4 ch)
    dim3 block(256);
    crop_pool_kernel<<<grid, block, 0, stream>>>(fm, corners, scale, out);
}

// Round 12
// 20.771 us; speedup vs baseline: 1.1655x; 1.1655x over previous
//
#include <hip/hip_runtime.h>
#include <math.h>

#define Bc 4
#define Cc 128
#define Pc 64
#define PLANE 576      // 24*24
#define VOL   13824    // 24^3
#define HALFOFF (64 * VOL)
#define NI    (-INFINITY)

// One wave per (proposal, channel-pair {slot, slot+64}).
// Zero-waste mapping: lane -> (ch = lane>=32, flat u = (lane&31) + 32K) over
// the crop's (h-row x w-quad) space of size G = n_h*Q; u clamped to G-1
// (duplicate of a REAL crop element -> no validity masks, max idempotent).
// Chunks C = ceil(G/32) in 1..5 (C==1 for ~70% of proposals), statically
// unrolled with wave-uniform guards. Per chunk-step: one global_load
// (scalar-advancing plane base + d-invariant per-lane byte offset),
// TREE x 2 regions + acc. d-region split = 3 uniform scalar segments.
// Epilogue: select-exchange reduce WITHIN each 32-lane half (A: lanes 0-31,
// B: lanes 32-63); lanes 0-7 / 32-39 store.

struct Acc { float v00, v01, v10, v11; };   // [d-region][w-region]

template<int RMODE>   // 0: d-region0, 1: d-region1, 2: both (overlap plane)
__device__ __forceinline__ void upd(Acc& a, float t0, float t1) {
    if (RMODE != 1) { a.v00 = fmaxf(a.v00, t0); a.v01 = fmaxf(a.v01, t1); }
    if (RMODE != 0) { a.v10 = fmaxf(a.v10, t0); a.v11 = fmaxf(a.v11, t1); }
}

#define TREE(v, B) fmaxf(fmaxf((v).x + (B).x, (v).y + (B).y),               \
                         fmaxf((v).z + (B).z, (v).w + (B).w))

__global__ __launch_bounds__(256) void crop_pool_kernel(
    const float* __restrict__ fm, const int* __restrict__ corners,
    const int* __restrict__ scale_p, float* __restrict__ out)
{
    const int lane = threadIdx.x & 63;
    const int wid  = threadIdx.x >> 6;   // 0..3
    const int bp   = blockIdx.x >> 4;    // 16 consecutive blocks per proposal
    const int slot = (blockIdx.x & 15) * 4 + wid;   // 0..63
    const int b    = bp >> 6;            // P = 64

    const float inv = 1.0f / (float)scale_p[0];   // uniform; exact-floor mul

    // Per-axis bounds (k: 0->D, 1->H, 2->W), uniform -> SGPR.
    int s[3], e[3], m0a[3], m1a[3];
#pragma unroll
    for (int k = 0; k < 3; ++k) {
        int c0 = corners[(bp * 2 + 0) * 3 + k];
        int c1 = corners[(bp * 2 + 1) * 3 + k];
        int p1v = (int)((float)c0 * inv);     // == c0/scale (c0 in [0,95])
        p1v = p1v > 21 ? 21 : p1v;
        int p2v = (int)((float)c1 * inv);
        if (p2v - p1v < 2) p2v = p1v + 2;
        int ee = p2v < 24 ? p2v : 24;
        int n  = ee - p1v;                    // 2..23
        s[k]   = __builtin_amdgcn_readfirstlane(p1v);
        e[k]   = __builtin_amdgcn_readfirstlane(ee);
        m0a[k] = __builtin_amdgcn_readfirstlane(p1v + ((n + 1) >> 1)); // r0 end
        m1a[k] = __builtin_amdgcn_readfirstlane(p1v + (n >> 1));       // r1 start
    }

    const int n0 = m1a[0] - s[0];            // d-segment lengths
    const int n1 = m0a[0] - m1a[0];
    const int n2 = e[0] - m0a[0];
    const int sh = s[1], nh = e[1] - s[1];
    const int m0h = m0a[1], m1h = m1a[1];
    const int sw = s[2], ew = e[2], m0w = m0a[2], m1w = m1a[2];

    const int qb = sw & ~3;                            // aligned w base
    const int Q  = ((sw & 3) + (ew - sw) + 3) >> 2;    // quads per row, 1..6
    const int G  = nh * Q;                             // useful slots/ch, 2..138
    const int C  = (G + 31) >> 5;                      // half-wave chunks, 1..5

    // 2^20 magic for /Q: exact for dividend <= 1024, divisor <= 512.
    const unsigned MQ = 1048576u / (unsigned)Q + 1u;

    const bool c1p = C > 1, c2p = C > 2, c3p = C > 3, c4p = C > 4;
    const int  lm  = lane & 31;
    const int  chB = lane >> 5;                        // 0: ch A, 1: ch B

    // Per-chunk d-invariant state: byte offset, h-masks. (Static names only.)
    int  vo0, vo1, vo2, vo3, vo4;
    bool h0m0, h0m1, h0m2, h0m3, h0m4;
    bool h1m0, h1m1, h1m2, h1m3, h1m4;
#define SETUP(K, VO, H0, H1) {                                              \
        int u = lm + (K << 5);                                              \
        u = u < G - 1 ? u : G - 1;          /* clamp to real element */     \
        const int r = (int)(((unsigned)u * MQ) >> 20);                      \
        const int q = u - r * Q;                                            \
        const int h = sh + r;                                               \
        VO = (chB * HALFOFF + h * 24 + qb + 4 * q) * 4;   /* bytes */       \
        H0 = h <  m0h;                                                      \
        H1 = h >= m1h;                                                      \
    }
    SETUP(0, vo0, h0m0, h1m0)
    if (c1p) SETUP(1, vo1, h0m1, h1m1) else { vo1 = vo0; h0m1 = false; h1m1 = false; }
    if (c2p) SETUP(2, vo2, h0m2, h1m2) else { vo2 = vo0; h0m2 = false; h1m2 = false; }
    if (c3p) SETUP(3, vo3, h0m3, h1m3) else { vo3 = vo0; h0m3 = false; h1m3 = false; }
    if (c4p) SETUP(4, vo4, h0m4, h1m4) else { vo4 = vo0; h0m4 = false; h1m4 = false; }
#undef SETUP

    // Shared w-biases (quad membership in the two w-regions)
    float4 B0, B1;
    {
        const int q0 = (lane < 32 ? 0 : 0);  (void)q0;
        // recompute this lane's q for chunk-independent biases? q varies per
        // chunk only through u; w-position = qb+4*q is chunk-dependent!
    }
    // NOTE: w-biases depend on q, which differs per chunk -> per-chunk biases.
    // To keep register cost low, biases are recomputed per chunk below from
    // the stored byte offset (w = (vo/4 - chB*HALFOFF) % 24).
    float4 B0c[1]; (void)B0c;

    // Per-chunk biases, static names.
#define WBIAS(VO, B0v, B1v) {                                               \
        const int fofs = (VO >> 2) - chB * HALFOFF;                         \
        const int hh   = (int)(((unsigned)fofs * 43691u) >> 20);  /* /24 */ \
        const int wb   = fofs - hh * 24;                                    \
        int wt;                                                             \
        wt = wb + 0; B0v.x = (wt >= sw  && wt < m0w) ? 0.0f : NI;           \
                     B1v.x = (wt >= m1w && wt < ew ) ? 0.0f : NI;           \
        wt = wb + 1; B0v.y = (wt >= sw  && wt < m0w) ? 0.0f : NI;           \
                     B1v.y = (wt >= m1w && wt < ew ) ? 0.0f : NI;           \
        wt = wb + 2; B0v.z = (wt >= sw  && wt < m0w) ? 0.0f : NI;           \
                     B1v.z = (wt >= m1w && wt < ew ) ? 0.0f : NI;           \
        wt = wb + 3; B0v.w = (wt >= sw  && wt < m0w) ? 0.0f : NI;           \
                     B1v.w = (wt >= m1w && wt < ew ) ? 0.0f : NI;           \
    }
    float4 Bw0_0, Bw1_0, Bw0_1, Bw1_1, Bw0_2, Bw1_2, Bw0_3, Bw1_3, Bw0_4, Bw1_4;
    WBIAS(vo0, Bw0_0, Bw1_0)
    if (c1p) WBIAS(vo1, Bw0_1, Bw1_1) else { Bw0_1 = Bw0_0; Bw1_1 = Bw1_0; }
    if (c2p) WBIAS(vo2, Bw0_2, Bw1_2) else { Bw0_2 = Bw0_0; Bw1_2 = Bw1_0; }
    if (c3p) WBIAS(vo3, Bw0_3, Bw1_3) else { Bw0_3 = Bw0_0; Bw1_3 = Bw1_0; }
    if (c4p) WBIAS(vo4, Bw0_4, Bw1_4) else { Bw0_4 = Bw0_0; Bw1_4 = Bw1_0; }
#undef WBIAS

    Acc a0, a1, a2, a3, a4;
    a0.v00=NI; a0.v01=NI; a0.v10=NI; a0.v11=NI;
    a1 = a0; a2 = a0; a3 = a0; a4 = a0;

    // Scalar-advancing plane base (channel A of this slot); ch offset is in vo.
    const char* sb = (const char*)(fm + ((size_t)(b * Cc + slot)) * VOL
                                      + (size_t)s[0] * PLANE);

#define CH(K, VO, A, BB0, BB1) {                                            \
        float4 v = *(const float4*)(sb + VO);                               \
        upd<RMODE>(A, TREE(v, BB0), TREE(v, BB1));                          \
    }
#define SEG(RM, N)                                                          \
    {                                                                       \
        constexpr int RMODE = RM;                                           \
        for (int i = 0; i < (N); ++i) {                                     \
            CH(0, vo0, a0, Bw0_0, Bw1_0)                                    \
            if (c1p) CH(1, vo1, a1, Bw0_1, Bw1_1)                           \
            if (c2p) CH(2, vo2, a2, Bw0_2, Bw1_2)                           \
            if (c3p) CH(3, vo3, a3, Bw0_3, Bw1_3)                           \
            if (c4p) CH(4, vo4, a4, Bw0_4, Bw1_4)                           \
            sb += PLANE * 4;                                                \
        }                                                                   \
    }

    SEG(0, n0)   // d-region 0 only
    SEG(2, n1)   // overlap plane (n_d odd)
    SEG(1, n2)   // d-region 1 only
#undef SEG
#undef CH

    // Merge chunks with h-masks into 8 octants j = dr*4 + hr*2 + wr.
    float o[8];
#pragma unroll
    for (int j = 0; j < 8; ++j) o[j] = NI;
#define MERGE(A, H0, H1) {                                                  \
        o[0] = fmaxf(o[0], H0 ? A.v00 : NI);                                \
        o[1] = fmaxf(o[1], H0 ? A.v01 : NI);                                \
        o[2] = fmaxf(o[2], H1 ? A.v00 : NI);                                \
        o[3] = fmaxf(o[3], H1 ? A.v01 : NI);                                \
        o[4] = fmaxf(o[4], H0 ? A.v10 : NI);                                \
        o[5] = fmaxf(o[5], H0 ? A.v11 : NI);                                \
        o[6] = fmaxf(o[6], H1 ? A.v10 : NI);                                \
        o[7] = fmaxf(o[7], H1 ? A.v11 : NI);                                \
    }
    MERGE(a0, h0m0, h1m0)
    if (c1p) MERGE(a1, h0m1, h1m1)
    if (c2p) MERGE(a2, h0m2, h1m2)
    if (c3p) MERGE(a3, h0m3, h1m3)
    if (c4p) MERGE(a4, h0m4, h1m4)
#undef MERGE

    // Select-exchange reduce WITHIN each 32-lane half (octant bit -> lane bit).
    const bool b0 = lane & 1, b1 = lane & 2, b2 = lane & 4;
    float m0_ = fmaxf(b0 ? o[1] : o[0], __shfl_xor(b0 ? o[0] : o[1], 1));
    float m1_ = fmaxf(b0 ? o[3] : o[2], __shfl_xor(b0 ? o[2] : o[3], 1));
    float m2_ = fmaxf(b0 ? o[5] : o[4], __shfl_xor(b0 ? o[4] : o[5], 1));
    float m3_ = fmaxf(b0 ? o[7] : o[6], __shfl_xor(b0 ? o[6] : o[7], 1));
    float p0_ = fmaxf(b1 ? m1_ : m0_, __shfl_xor(b1 ? m0_ : m1_, 2));
    float p1_ = fmaxf(b1 ? m3_ : m2_, __shfl_xor(b1 ? m2_ : m3_, 2));
    float v   = fmaxf(b2 ? p1_ : p0_, __shfl_xor(b2 ? p0_ : p1_, 4));
    v = fmaxf(v, __shfl_xor(v, 8));
    v = fmaxf(v, __shfl_xor(v, 16));   // no xor-32: halves stay independent

    if ((lane & 31) < 8) {
        const int cc = slot + (chB << 6);   // A: slot, B: slot+64
        out[((size_t)bp * Cc + cc) * 8 + (lane & 7)] = v;
    }
}

extern "C" void kernel_launch(void* const* d_in, const int* in_sizes, int n_in,
                              void* d_out, int out_size, void* d_ws, size_t ws_size,
                              hipStream_t stream) {
    const float* fm      = (const float*)d_in[0];
    const int*   corners = (const int*)d_in[1];
    const int*   scale   = (const int*)d_in[2];
    float*       out     = (float*)d_out;

    dim3 grid(Bc * Pc * 16);   // 4096 blocks: one wave per (proposal, ch-pair)
    dim3 block(256);
    crop_pool_kernel<<<grid, block, 0, stream>>>(fm, corners, scale, out);
}